// Round 9
// baseline (111.869 us; speedup 1.0000x reference)
//
#include <hip/hip_runtime.h>
#include <cstdint>

// Problem constants (match reference)
#define Bn 8
#define Ln 4096
#define Dn 2048
#define Gn 32
#define GSn 64
#define TROWS 128               // timesteps per tile: 1024 threads x (2 rows) x 16 lanes
#define NT (Ln / TROWS)         // 32 tiles per chain
static constexpr float EPS = 1e-5f;

// ---------------------------------------------------------------------------
// One block per (b,g) chain, single pass, ONE barrier per tile.
// Thread (pr,k): rows {2pr, 2pr+1} of the tile, 16 lanes x float4 = 64 cols.
// Per tile: row group-means via shfl_xor; pair-combine; in-wave scan over 4
// pairs; wave leaders post (S,Q,P) totals to double-buffered LDS; barrier;
// EVERY wave scans the 16 totals in-register (no 2nd barrier); closed-form
// Welford -> normalize in registers -> store y.
// x read once, y written once; no workspace, no grid sync.
// mask (bool) and prev_count (int64) are pushed by the harness as int32.
// ---------------------------------------------------------------------------
__global__ __launch_bounds__(1024, 1) void fused_chain(
    const float* __restrict__ x,
    const int* __restrict__ mask,
    const int* __restrict__ prev_count,
    const float* __restrict__ prev_mean,
    const float* __restrict__ prev_var,
    const float* __restrict__ weight,
    const float* __restrict__ bias,
    float* __restrict__ y,
    float* __restrict__ out_count,
    float* __restrict__ out_mean,
    float* __restrict__ out_var)
{
    const int bg  = blockIdx.x;      // b*G + g
    const int b   = bg >> 5;
    const int g   = bg & 31;
    const int tid = threadIdx.x;
    const int pr   = tid >> 4;       // pair index 0..63 (rows 2pr, 2pr+1)
    const int k    = tid & 15;       // 16 lanes per row
    const int lane = tid & 63;
    const int wv   = tid >> 6;       // wave 0..15

    const size_t xbase = (size_t)b * Ln * Dn + g * GSn + k * 4;
    const int    mbase = b * Ln;

    const float4 wv4 = *reinterpret_cast<const float4*>(weight + g * GSn + k * 4);
    const float4 bv4 = *reinterpret_cast<const float4*>(bias   + g * GSn + k * 4);

    const float c0  = (float)prev_count[b];
    const float mu0 = prev_mean[bg];
    const float v0  = prev_var[bg];
    const float A0  = c0 * mu0;
    const float M2b = v0 * fmaxf(c0, 1.f) + c0 * mu0 * mu0;

    __shared__ float wTot[2][3][16];   // double-buffered per-wave totals

    float carS = 0.f, carQ = 0.f, carP = 0.f;   // carry across tiles (uniform)

    // prefetch tile 0
    float4 x0 = *reinterpret_cast<const float4*>(x + xbase + (size_t)(2 * pr)     * Dn);
    float4 x1 = *reinterpret_cast<const float4*>(x + xbase + (size_t)(2 * pr + 1) * Dn);
    int2   mk = *reinterpret_cast<const int2*>(mask + mbase + 2 * pr);

    for (int it = 0; it < NT; ++it) {
        // ---- prefetch next tile (2 rows; 32KB/block in flight)
        const int rn = (it + 1 < NT) ? ((it + 1) * TROWS + 2 * pr) : 2 * pr;
        float4 nx0 = *reinterpret_cast<const float4*>(x + xbase + (size_t)rn       * Dn);
        float4 nx1 = *reinterpret_cast<const float4*>(x + xbase + (size_t)(rn + 1) * Dn);
        int2   nmk = *reinterpret_cast<const int2*>(mask + mbase + rn);

        // ---- row group-means (reduce 16 lanes)
        float s0 = (x0.x + x0.y) + (x0.z + x0.w);
        float s1 = (x1.x + x1.y) + (x1.z + x1.w);
        s0 += __shfl_xor(s0, 1);  s1 += __shfl_xor(s1, 1);
        s0 += __shfl_xor(s0, 2);  s1 += __shfl_xor(s1, 2);
        s0 += __shfl_xor(s0, 4);  s1 += __shfl_xor(s1, 4);
        s0 += __shfl_xor(s0, 8);  s1 += __shfl_xor(s1, 8);
        const float m0 = s0 * (1.f / (float)GSn);
        const float m1 = s1 * (1.f / (float)GSn);
        const float k0 = mk.x ? 1.f : 0.f;
        const float k1 = mk.y ? 1.f : 0.f;

        // ---- pair partials
        const float pS = k0 * m0 + k1 * m1;
        const float pQ = k0 * m0 * m0 + k1 * m1 * m1;
        const float pP = k0 + k1;

        // ---- in-wave inclusive scan over 4 pairs (16-lane groups)
        float iS = pS, iQ = pQ, iP = pP;
        {
            float u;
            u = __shfl_up(iS, 16); if (lane >= 16) iS += u;
            u = __shfl_up(iQ, 16); if (lane >= 16) iQ += u;
            u = __shfl_up(iP, 16); if (lane >= 16) iP += u;
            u = __shfl_up(iS, 32); if (lane >= 32) iS += u;
            u = __shfl_up(iQ, 32); if (lane >= 32) iQ += u;
            u = __shfl_up(iP, 32); if (lane >= 32) iP += u;
        }

        const int p = it & 1;
        if (lane == 63) { wTot[p][0][wv] = iS; wTot[p][1][wv] = iQ; wTot[p][2][wv] = iP; }
        __syncthreads();

        // ---- every wave scans the 16 wave-totals in-register (no 2nd barrier)
        float tS = wTot[p][0][k];
        float tQ = wTot[p][1][k];
        float tP = wTot[p][2][k];
#pragma unroll
        for (int off = 1; off < 16; off <<= 1) {
            float u;
            u = __shfl_up(tS, off, 16); if (k >= off) tS += u;
            u = __shfl_up(tQ, off, 16); if (k >= off) tQ += u;
            u = __shfl_up(tP, off, 16); if (k >= off) tP += u;
        }
        const float tileS = __shfl(tS, 15, 16);
        const float tileQ = __shfl(tQ, 15, 16);
        const float tileP = __shfl(tP, 15, 16);
        const int j = (wv == 0) ? 0 : wv - 1;
        float exS = __shfl(tS, j, 16);
        float exQ = __shfl(tQ, j, 16);
        float exP = __shfl(tP, j, 16);
        if (wv == 0) { exS = 0.f; exQ = 0.f; exP = 0.f; }

        // ---- inclusive prefixes: row 2pr+1 then derive row 2pr
        const float S1 = carS + exS + iS;
        const float Q1 = carQ + exQ + iQ;
        const float P1 = carP + exP + iP;
        const float S0 = S1 - k1 * m1;
        const float Q0 = Q1 - k1 * m1 * m1;
        const float P0 = P1 - k1;

        const float rc0 = __builtin_amdgcn_rcpf(fmaxf(c0 + P0, 1.f));
        const float me0 = (A0 + S0) * rc0;
        const float rs0 = rsqrtf((M2b + Q0) * rc0 - me0 * me0 + EPS);
        const float rc1 = __builtin_amdgcn_rcpf(fmaxf(c0 + P1, 1.f));
        const float me1 = (A0 + S1) * rc1;
        const float rs1 = rsqrtf((M2b + Q1) * rc1 - me1 * me1 + EPS);

        // ---- normalize + affine, store both rows
        float4 o0, o1;
        o0.x = (x0.x - me0) * rs0 * wv4.x + bv4.x;
        o0.y = (x0.y - me0) * rs0 * wv4.y + bv4.y;
        o0.z = (x0.z - me0) * rs0 * wv4.z + bv4.z;
        o0.w = (x0.w - me0) * rs0 * wv4.w + bv4.w;
        o1.x = (x1.x - me1) * rs1 * wv4.x + bv4.x;
        o1.y = (x1.y - me1) * rs1 * wv4.y + bv4.y;
        o1.z = (x1.z - me1) * rs1 * wv4.z + bv4.z;
        o1.w = (x1.w - me1) * rs1 * wv4.w + bv4.w;
        const size_t yrow = xbase + (size_t)(it * TROWS + 2 * pr) * Dn;
        *reinterpret_cast<float4*>(y + yrow)      = o0;
        *reinterpret_cast<float4*>(y + yrow + Dn) = o1;

        // ---- advance carry (uniform), rotate prefetch
        carS += tileS; carQ += tileQ; carP += tileP;
        x0 = nx0; x1 = nx1; mk = nmk;
    }

    if (tid == 0) {
        const float c  = c0 + carP;
        const float cs = fmaxf(c, 1.f);
        const float mean = (A0 + carS) / cs;
        out_mean[bg] = mean;
        out_var[bg]  = (M2b + carQ) / cs - mean * mean;
        if (g == 0) out_count[b] = c;
    }
}

// ---------------------------------------------------------------------------
extern "C" void kernel_launch(void* const* d_in, const int* in_sizes, int n_in,
                              void* d_out, int out_size, void* d_ws, size_t ws_size,
                              hipStream_t stream) {
    (void)in_sizes; (void)n_in; (void)out_size; (void)d_ws; (void)ws_size;

    const float* x          = (const float*)d_in[0];
    const int*   mask       = (const int*)d_in[1];     // bool pushed as int32
    const int*   prev_count = (const int*)d_in[2];     // int pushed as int32
    const float* prev_mean  = (const float*)d_in[3];
    const float* prev_var   = (const float*)d_in[4];
    const float* weight     = (const float*)d_in[5];
    const float* bias       = (const float*)d_in[6];

    float* out = (float*)d_out;
    float* y         = out;                                   // B*L*D
    float* out_count = out + (size_t)Bn * Ln * Dn;            // B
    float* out_mean  = out_count + Bn;                        // B*G
    float* out_var   = out_mean + (size_t)Bn * Gn;            // B*G

    fused_chain<<<Bn * Gn, 1024, 0, stream>>>(x, mask, prev_count, prev_mean,
                                              prev_var, weight, bias, y,
                                              out_count, out_mean, out_var);
}

// Round 10
// 109.380 us; speedup vs baseline: 1.0228x; 1.0228x over previous
//
#include <hip/hip_runtime.h>
#include <cstdint>

// Problem constants (match reference)
#define Bn 8
#define Ln 4096
#define Dn 2048
#define Gn 32
#define GSn 64
#define TROWS 128               // timesteps per tile: 1024 threads x (2 rows) x 16 lanes
#define NT (Ln / TROWS)         // 32 tiles per chain
static constexpr float EPS = 1e-5f;

// Raw barrier: orders only LDS (lgkmcnt), NOT vmcnt — prefetched global loads
// stay in flight across it. __syncthreads() would drain vmcnt(0) per tile and
// expose a full HBM round-trip (round-9 lesson: 1 block/CU has nothing else
// to hide that stall under). Compiler fences stop LDS ops crossing.
#define LDS_BARRIER()                                            \
    do {                                                         \
        asm volatile("s_waitcnt lgkmcnt(0)" ::: "memory");       \
        __builtin_amdgcn_s_barrier();                            \
        asm volatile("" ::: "memory");                           \
    } while (0)

// ---------------------------------------------------------------------------
// One block per (b,g) chain, single pass, one raw barrier per tile, prefetch
// depth 2 (x held in registers; ~64KB/block of loads in flight).
// Thread (pr,k): rows {2pr, 2pr+1}; 16 lanes x float4 = 64 cols (one group).
// Per tile: row group-means (shfl_xor); pair partials; in-wave scan over 4
// pairs; leaders post (S,Q,P) to double-buffered LDS; LDS_BARRIER; every wave
// redundantly scans the 16 totals in-register; closed-form Welford; normalize
// in registers; store y. x read once, y written once; no workspace.
// mask (bool) and prev_count (int64) are pushed by the harness as int32.
// ---------------------------------------------------------------------------
__global__ __launch_bounds__(1024, 1) void fused_chain(
    const float* __restrict__ x,
    const int* __restrict__ mask,
    const int* __restrict__ prev_count,
    const float* __restrict__ prev_mean,
    const float* __restrict__ prev_var,
    const float* __restrict__ weight,
    const float* __restrict__ bias,
    float* __restrict__ y,
    float* __restrict__ out_count,
    float* __restrict__ out_mean,
    float* __restrict__ out_var)
{
    const int bg  = blockIdx.x;      // b*G + g
    const int b   = bg >> 5;
    const int g   = bg & 31;
    const int tid = threadIdx.x;
    const int pr   = tid >> 4;       // pair index 0..63 (rows 2pr, 2pr+1)
    const int k    = tid & 15;       // 16 lanes per row
    const int lane = tid & 63;
    const int wv   = tid >> 6;       // wave 0..15

    const size_t xbase = (size_t)b * Ln * Dn + g * GSn + k * 4;
    const int    mbase = b * Ln;

    const float4 wv4 = *reinterpret_cast<const float4*>(weight + g * GSn + k * 4);
    const float4 bv4 = *reinterpret_cast<const float4*>(bias   + g * GSn + k * 4);

    const float c0  = (float)prev_count[b];
    const float mu0 = prev_mean[bg];
    const float v0  = prev_var[bg];
    const float A0  = c0 * mu0;
    const float M2b = v0 * fmaxf(c0, 1.f) + c0 * mu0 * mu0;

    __shared__ float wTot[2][3][16];   // double-buffered per-wave totals
                                       // (read of buf p and next write of buf p
                                       //  are separated by 2 barriers -> safe)

    float carS = 0.f, carQ = 0.f, carP = 0.f;   // carry across tiles (uniform)

    // prefetch tiles 0 and 1
    float4 x0 = *reinterpret_cast<const float4*>(x + xbase + (size_t)(2 * pr)     * Dn);
    float4 x1 = *reinterpret_cast<const float4*>(x + xbase + (size_t)(2 * pr + 1) * Dn);
    int2   mk = *reinterpret_cast<const int2*>(mask + mbase + 2 * pr);
    float4 p0 = *reinterpret_cast<const float4*>(x + xbase + (size_t)(TROWS + 2 * pr)     * Dn);
    float4 p1 = *reinterpret_cast<const float4*>(x + xbase + (size_t)(TROWS + 2 * pr + 1) * Dn);
    int2   pmk = *reinterpret_cast<const int2*>(mask + mbase + TROWS + 2 * pr);

    for (int it = 0; it < NT; ++it) {
        // ---- issue prefetch for tile it+2 (completes under ~2 tiles of work)
        const int rn = (it + 2 < NT) ? ((it + 2) * TROWS + 2 * pr) : 2 * pr;
        float4 q0 = *reinterpret_cast<const float4*>(x + xbase + (size_t)rn       * Dn);
        float4 q1 = *reinterpret_cast<const float4*>(x + xbase + (size_t)(rn + 1) * Dn);
        int2   qmk = *reinterpret_cast<const int2*>(mask + mbase + rn);

        // ---- row group-means (reduce 16 lanes)
        float s0 = (x0.x + x0.y) + (x0.z + x0.w);
        float s1 = (x1.x + x1.y) + (x1.z + x1.w);
        s0 += __shfl_xor(s0, 1);  s1 += __shfl_xor(s1, 1);
        s0 += __shfl_xor(s0, 2);  s1 += __shfl_xor(s1, 2);
        s0 += __shfl_xor(s0, 4);  s1 += __shfl_xor(s1, 4);
        s0 += __shfl_xor(s0, 8);  s1 += __shfl_xor(s1, 8);
        const float m0 = s0 * (1.f / (float)GSn);
        const float m1 = s1 * (1.f / (float)GSn);
        const float k0 = mk.x ? 1.f : 0.f;
        const float k1 = mk.y ? 1.f : 0.f;

        // ---- pair partials
        const float pS = k0 * m0 + k1 * m1;
        const float pQ = k0 * m0 * m0 + k1 * m1 * m1;
        const float pP = k0 + k1;

        // ---- in-wave inclusive scan over 4 pairs (16-lane groups)
        float iS = pS, iQ = pQ, iP = pP;
        {
            float u;
            u = __shfl_up(iS, 16); if (lane >= 16) iS += u;
            u = __shfl_up(iQ, 16); if (lane >= 16) iQ += u;
            u = __shfl_up(iP, 16); if (lane >= 16) iP += u;
            u = __shfl_up(iS, 32); if (lane >= 32) iS += u;
            u = __shfl_up(iQ, 32); if (lane >= 32) iQ += u;
            u = __shfl_up(iP, 32); if (lane >= 32) iP += u;
        }

        const int p = it & 1;
        if (lane == 63) { wTot[p][0][wv] = iS; wTot[p][1][wv] = iQ; wTot[p][2][wv] = iP; }
        LDS_BARRIER();

        // ---- every wave scans the 16 wave-totals in-register (no 2nd barrier)
        float tS = wTot[p][0][k];
        float tQ = wTot[p][1][k];
        float tP = wTot[p][2][k];
#pragma unroll
        for (int off = 1; off < 16; off <<= 1) {
            float u;
            u = __shfl_up(tS, off, 16); if (k >= off) tS += u;
            u = __shfl_up(tQ, off, 16); if (k >= off) tQ += u;
            u = __shfl_up(tP, off, 16); if (k >= off) tP += u;
        }
        const float tileS = __shfl(tS, 15, 16);
        const float tileQ = __shfl(tQ, 15, 16);
        const float tileP = __shfl(tP, 15, 16);
        const int j = (wv == 0) ? 0 : wv - 1;
        float exS = __shfl(tS, j, 16);
        float exQ = __shfl(tQ, j, 16);
        float exP = __shfl(tP, j, 16);
        if (wv == 0) { exS = 0.f; exQ = 0.f; exP = 0.f; }

        // ---- inclusive prefixes: row 2pr+1 then derive row 2pr
        const float S1 = carS + exS + iS;
        const float Q1 = carQ + exQ + iQ;
        const float P1 = carP + exP + iP;
        const float S0 = S1 - k1 * m1;
        const float Q0 = Q1 - k1 * m1 * m1;
        const float P0 = P1 - k1;

        const float rc0 = __builtin_amdgcn_rcpf(fmaxf(c0 + P0, 1.f));
        const float me0 = (A0 + S0) * rc0;
        const float rs0 = rsqrtf((M2b + Q0) * rc0 - me0 * me0 + EPS);
        const float rc1 = __builtin_amdgcn_rcpf(fmaxf(c0 + P1, 1.f));
        const float me1 = (A0 + S1) * rc1;
        const float rs1 = rsqrtf((M2b + Q1) * rc1 - me1 * me1 + EPS);

        // ---- normalize + affine, store both rows
        float4 o0, o1;
        o0.x = (x0.x - me0) * rs0 * wv4.x + bv4.x;
        o0.y = (x0.y - me0) * rs0 * wv4.y + bv4.y;
        o0.z = (x0.z - me0) * rs0 * wv4.z + bv4.z;
        o0.w = (x0.w - me0) * rs0 * wv4.w + bv4.w;
        o1.x = (x1.x - me1) * rs1 * wv4.x + bv4.x;
        o1.y = (x1.y - me1) * rs1 * wv4.y + bv4.y;
        o1.z = (x1.z - me1) * rs1 * wv4.z + bv4.z;
        o1.w = (x1.w - me1) * rs1 * wv4.w + bv4.w;
        const size_t yrow = xbase + (size_t)(it * TROWS + 2 * pr) * Dn;
        *reinterpret_cast<float4*>(y + yrow)      = o0;
        *reinterpret_cast<float4*>(y + yrow + Dn) = o1;

        // ---- advance carry (uniform), rotate prefetch pipeline
        carS += tileS; carQ += tileQ; carP += tileP;
        x0 = p0; x1 = p1; mk = pmk;
        p0 = q0; p1 = q1; pmk = qmk;
    }

    if (tid == 0) {
        const float c  = c0 + carP;
        const float cs = fmaxf(c, 1.f);
        const float mean = (A0 + carS) / cs;
        out_mean[bg] = mean;
        out_var[bg]  = (M2b + carQ) / cs - mean * mean;
        if (g == 0) out_count[b] = c;
    }
}

// ---------------------------------------------------------------------------
extern "C" void kernel_launch(void* const* d_in, const int* in_sizes, int n_in,
                              void* d_out, int out_size, void* d_ws, size_t ws_size,
                              hipStream_t stream) {
    (void)in_sizes; (void)n_in; (void)out_size; (void)d_ws; (void)ws_size;

    const float* x          = (const float*)d_in[0];
    const int*   mask       = (const int*)d_in[1];     // bool pushed as int32
    const int*   prev_count = (const int*)d_in[2];     // int pushed as int32
    const float* prev_mean  = (const float*)d_in[3];
    const float* prev_var   = (const float*)d_in[4];
    const float* weight     = (const float*)d_in[5];
    const float* bias       = (const float*)d_in[6];

    float* out = (float*)d_out;
    float* y         = out;                                   // B*L*D
    float* out_count = out + (size_t)Bn * Ln * Dn;            // B
    float* out_mean  = out_count + Bn;                        // B*G
    float* out_var   = out_mean + (size_t)Bn * Gn;            // B*G

    fused_chain<<<Bn * Gn, 1024, 0, stream>>>(x, mask, prev_count, prev_mean,
                                              prev_var, weight, bias, y,
                                              out_count, out_mean, out_var);
}

// Round 12
// 107.921 us; speedup vs baseline: 1.0366x; 1.0135x over previous
//
#include <hip/hip_runtime.h>
#include <cstdint>

// Problem constants (match reference)
#define Bn 8
#define Ln 4096
#define Dn 2048
#define Gn 32
#define GSn 64
#define TROWS 256               // timesteps per tile: 1024 threads x (4 rows) x 16 lanes
#define NT (Ln / TROWS)         // 16 tiles per chain
static constexpr float EPS = 1e-5f;

// Native vector type for nontemporal builtins (HIP_vector_type float4 is
// rejected by __builtin_nontemporal_*; ext_vector_type is accepted and
// layout-identical).
typedef float f4 __attribute__((ext_vector_type(4)));

// Raw barrier: orders only LDS (lgkmcnt), NOT vmcnt — prefetched global loads
// stay in flight across it (round-10 structure; __syncthreads would drain
// vmcnt(0) per tile with nothing to hide the stall under at 1 block/CU).
#define LDS_BARRIER()                                            \
    do {                                                         \
        asm volatile("s_waitcnt lgkmcnt(0)" ::: "memory");       \
        __builtin_amdgcn_s_barrier();                            \
        asm volatile("" ::: "memory");                           \
    } while (0)

// ---------------------------------------------------------------------------
// One block per (b,g) chain, single pass. Thread (pr,k): rows 4pr..4pr+3 of
// the tile, 16 lanes x f4 = 64 cols (one group). Per tile: 4 row group-means
// (shfl_xor butterfly within 16-lane groups); thread-local (S,Q,P) over its 4
// rows; in-wave scan across the 4 sub-groups; wave leaders post totals to
// double-buffered LDS; LDS_BARRIER; every wave redundantly scans the 16 wave
// totals in-register; closed-form Welford per row; normalize in registers;
// nontemporal store. x and y are touch-once streams -> nt hints.
// x read once, y written once; no workspace, no grid sync.
// mask (bool) and prev_count (int64) are pushed by the harness as int32.
// ---------------------------------------------------------------------------
__global__ __launch_bounds__(1024, 1) void fused_chain(
    const float* __restrict__ x,
    const int* __restrict__ mask,
    const int* __restrict__ prev_count,
    const float* __restrict__ prev_mean,
    const float* __restrict__ prev_var,
    const float* __restrict__ weight,
    const float* __restrict__ bias,
    float* __restrict__ y,
    float* __restrict__ out_count,
    float* __restrict__ out_mean,
    float* __restrict__ out_var)
{
    const int bg  = blockIdx.x;      // b*G + g
    const int b   = bg >> 5;
    const int g   = bg & 31;
    const int tid = threadIdx.x;
    const int k    = tid & 15;       // 16 lanes per row
    const int pr   = tid >> 4;       // quad index 0..63 (rows 4pr..4pr+3)
    const int lane = tid & 63;
    const int wv   = tid >> 6;       // wave 0..15

    const size_t xbase = (size_t)b * Ln * Dn + g * GSn + k * 4;
    const int    mbase = b * Ln;

    const f4 wv4 = *reinterpret_cast<const f4*>(weight + g * GSn + k * 4);
    const f4 bv4 = *reinterpret_cast<const f4*>(bias   + g * GSn + k * 4);

    const float c0  = (float)prev_count[b];
    const float mu0 = prev_mean[bg];
    const float v0  = prev_var[bg];
    const float A0  = c0 * mu0;
    const float M2b = v0 * fmaxf(c0, 1.f) + c0 * mu0 * mu0;

    __shared__ float wTot[2][3][16];   // double-buffered per-wave totals

    float carS = 0.f, carQ = 0.f, carP = 0.f;   // carry across tiles (uniform)

    // prefetch tile 0 (4 rows/thread, nontemporal: touch-once stream)
    f4 xc0, xc1, xc2, xc3;
    int4 mkc;
    {
        const int r0 = 4 * pr;
        xc0 = __builtin_nontemporal_load(reinterpret_cast<const f4*>(x + xbase + (size_t)(r0 + 0) * Dn));
        xc1 = __builtin_nontemporal_load(reinterpret_cast<const f4*>(x + xbase + (size_t)(r0 + 1) * Dn));
        xc2 = __builtin_nontemporal_load(reinterpret_cast<const f4*>(x + xbase + (size_t)(r0 + 2) * Dn));
        xc3 = __builtin_nontemporal_load(reinterpret_cast<const f4*>(x + xbase + (size_t)(r0 + 3) * Dn));
        mkc = *reinterpret_cast<const int4*>(mask + mbase + r0);
    }

    for (int it = 0; it < NT; ++it) {
        // ---- issue prefetch for tile it+1 (consumed after a full tile of work)
        const int rn = (it + 1 < NT) ? ((it + 1) * TROWS + 4 * pr) : 4 * pr;
        f4 xn0 = __builtin_nontemporal_load(reinterpret_cast<const f4*>(x + xbase + (size_t)(rn + 0) * Dn));
        f4 xn1 = __builtin_nontemporal_load(reinterpret_cast<const f4*>(x + xbase + (size_t)(rn + 1) * Dn));
        f4 xn2 = __builtin_nontemporal_load(reinterpret_cast<const f4*>(x + xbase + (size_t)(rn + 2) * Dn));
        f4 xn3 = __builtin_nontemporal_load(reinterpret_cast<const f4*>(x + xbase + (size_t)(rn + 3) * Dn));
        int4 mkn = *reinterpret_cast<const int4*>(mask + mbase + rn);

        // ---- row group-means (butterfly over 16 lanes; all lanes get the sum)
        float s0 = (xc0.x + xc0.y) + (xc0.z + xc0.w);
        float s1 = (xc1.x + xc1.y) + (xc1.z + xc1.w);
        float s2 = (xc2.x + xc2.y) + (xc2.z + xc2.w);
        float s3 = (xc3.x + xc3.y) + (xc3.z + xc3.w);
#pragma unroll
        for (int off = 1; off < 16; off <<= 1) {
            s0 += __shfl_xor(s0, off);
            s1 += __shfl_xor(s1, off);
            s2 += __shfl_xor(s2, off);
            s3 += __shfl_xor(s3, off);
        }
        const float m0 = s0 * (1.f / (float)GSn);
        const float m1 = s1 * (1.f / (float)GSn);
        const float m2 = s2 * (1.f / (float)GSn);
        const float m3 = s3 * (1.f / (float)GSn);
        const float k0 = mkc.x ? 1.f : 0.f;
        const float k1 = mkc.y ? 1.f : 0.f;
        const float k2 = mkc.z ? 1.f : 0.f;
        const float k3 = mkc.w ? 1.f : 0.f;

        // ---- thread-local partials over its 4 rows
        const float S = k0 * m0 + k1 * m1 + k2 * m2 + k3 * m3;
        const float Q = k0 * m0 * m0 + k1 * m1 * m1 + k2 * m2 * m2 + k3 * m3 * m3;
        const float P = k0 + k1 + k2 + k3;

        // ---- in-wave inclusive scan across the 4 sub-groups (16-lane each)
        float iS = S, iQ = Q, iP = P;
        {
            float u;
            u = __shfl_up(iS, 16); if (lane >= 16) iS += u;
            u = __shfl_up(iQ, 16); if (lane >= 16) iQ += u;
            u = __shfl_up(iP, 16); if (lane >= 16) iP += u;
            u = __shfl_up(iS, 32); if (lane >= 32) iS += u;
            u = __shfl_up(iQ, 32); if (lane >= 32) iQ += u;
            u = __shfl_up(iP, 32); if (lane >= 32) iP += u;
        }

        const int p = it & 1;
        if (lane == 63) { wTot[p][0][wv] = iS; wTot[p][1][wv] = iQ; wTot[p][2][wv] = iP; }
        LDS_BARRIER();

        // ---- every wave scans the 16 wave totals in-register
        float tS = wTot[p][0][k];
        float tQ = wTot[p][1][k];
        float tP = wTot[p][2][k];
#pragma unroll
        for (int off = 1; off < 16; off <<= 1) {
            float u;
            u = __shfl_up(tS, off, 16); if (k >= off) tS += u;
            u = __shfl_up(tQ, off, 16); if (k >= off) tQ += u;
            u = __shfl_up(tP, off, 16); if (k >= off) tP += u;
        }
        const float tileS = __shfl(tS, 15, 16);
        const float tileQ = __shfl(tQ, 15, 16);
        const float tileP = __shfl(tP, 15, 16);
        const int j = (wv == 0) ? 0 : wv - 1;
        float exS = __shfl(tS, j, 16);
        float exQ = __shfl(tQ, j, 16);
        float exP = __shfl(tP, j, 16);
        if (wv == 0) { exS = 0.f; exQ = 0.f; exP = 0.f; }

        // ---- running prefix for this thread's 4 rows, Welford + store
        float bS = carS + exS + (iS - S);
        float bQ = carQ + exQ + (iQ - Q);
        float bP = carP + exP + (iP - P);
        const size_t yrow = xbase + (size_t)(it * TROWS + 4 * pr) * Dn;

        {
            bS += k0 * m0; bQ += k0 * m0 * m0; bP += k0;
            const float rc = __builtin_amdgcn_rcpf(fmaxf(c0 + bP, 1.f));
            const float me = (A0 + bS) * rc;
            const float rs = rsqrtf((M2b + bQ) * rc - me * me + EPS);
            f4 o;
            o.x = (xc0.x - me) * rs * wv4.x + bv4.x;
            o.y = (xc0.y - me) * rs * wv4.y + bv4.y;
            o.z = (xc0.z - me) * rs * wv4.z + bv4.z;
            o.w = (xc0.w - me) * rs * wv4.w + bv4.w;
            __builtin_nontemporal_store(o, reinterpret_cast<f4*>(y + yrow));
        }
        {
            bS += k1 * m1; bQ += k1 * m1 * m1; bP += k1;
            const float rc = __builtin_amdgcn_rcpf(fmaxf(c0 + bP, 1.f));
            const float me = (A0 + bS) * rc;
            const float rs = rsqrtf((M2b + bQ) * rc - me * me + EPS);
            f4 o;
            o.x = (xc1.x - me) * rs * wv4.x + bv4.x;
            o.y = (xc1.y - me) * rs * wv4.y + bv4.y;
            o.z = (xc1.z - me) * rs * wv4.z + bv4.z;
            o.w = (xc1.w - me) * rs * wv4.w + bv4.w;
            __builtin_nontemporal_store(o, reinterpret_cast<f4*>(y + yrow + Dn));
        }
        {
            bS += k2 * m2; bQ += k2 * m2 * m2; bP += k2;
            const float rc = __builtin_amdgcn_rcpf(fmaxf(c0 + bP, 1.f));
            const float me = (A0 + bS) * rc;
            const float rs = rsqrtf((M2b + bQ) * rc - me * me + EPS);
            f4 o;
            o.x = (xc2.x - me) * rs * wv4.x + bv4.x;
            o.y = (xc2.y - me) * rs * wv4.y + bv4.y;
            o.z = (xc2.z - me) * rs * wv4.z + bv4.z;
            o.w = (xc2.w - me) * rs * wv4.w + bv4.w;
            __builtin_nontemporal_store(o, reinterpret_cast<f4*>(y + yrow + 2 * Dn));
        }
        {
            bS += k3 * m3; bQ += k3 * m3 * m3; bP += k3;
            const float rc = __builtin_amdgcn_rcpf(fmaxf(c0 + bP, 1.f));
            const float me = (A0 + bS) * rc;
            const float rs = rsqrtf((M2b + bQ) * rc - me * me + EPS);
            f4 o;
            o.x = (xc3.x - me) * rs * wv4.x + bv4.x;
            o.y = (xc3.y - me) * rs * wv4.y + bv4.y;
            o.z = (xc3.z - me) * rs * wv4.z + bv4.z;
            o.w = (xc3.w - me) * rs * wv4.w + bv4.w;
            __builtin_nontemporal_store(o, reinterpret_cast<f4*>(y + yrow + 3 * Dn));
        }

        // ---- advance carry (uniform), rotate prefetch
        carS += tileS; carQ += tileQ; carP += tileP;
        xc0 = xn0; xc1 = xn1; xc2 = xn2; xc3 = xn3; mkc = mkn;
    }

    if (tid == 0) {
        const float c  = c0 + carP;
        const float cs = fmaxf(c, 1.f);
        const float mean = (A0 + carS) / cs;
        out_mean[bg] = mean;
        out_var[bg]  = (M2b + carQ) / cs - mean * mean;
        if (g == 0) out_count[b] = c;
    }
}

// ---------------------------------------------------------------------------
extern "C" void kernel_launch(void* const* d_in, const int* in_sizes, int n_in,
                              void* d_out, int out_size, void* d_ws, size_t ws_size,
                              hipStream_t stream) {
    (void)in_sizes; (void)n_in; (void)out_size; (void)d_ws; (void)ws_size;

    const float* x          = (const float*)d_in[0];
    const int*   mask       = (const int*)d_in[1];     // bool pushed as int32
    const int*   prev_count = (const int*)d_in[2];     // int pushed as int32
    const float* prev_mean  = (const float*)d_in[3];
    const float* prev_var   = (const float*)d_in[4];
    const float* weight     = (const float*)d_in[5];
    const float* bias       = (const float*)d_in[6];

    float* out = (float*)d_out;
    float* y         = out;                                   // B*L*D
    float* out_count = out + (size_t)Bn * Ln * Dn;            // B
    float* out_mean  = out_count + Bn;                        // B*G
    float* out_var   = out_mean + (size_t)Bn * Gn;            // B*G

    fused_chain<<<Bn * Gn, 1024, 0, stream>>>(x, mask, prev_count, prev_mean,
                                              prev_var, weight, bias, y,
                                              out_count, out_mean, out_var);
}